// Round 6
// baseline (275.939 us; speedup 1.0000x reference)
//
#include <hip/hip_runtime.h>
#include <hip/hip_bf16.h>

#define N_ROI 512
#define M_REF 4096
#define FEAT 1024
#define GROUP 16
#define DG 64
#define EMB 64
#define GLDH 72   // gemm LDS row stride (halfs)
#define MSPLIT 8
#define MRANGE (M_REF / MSPLIT)  // 512
#define MCHUNK 128
#define BP2 136   // bias LDS m-stride (halfs)
#define PTP 40    // P-transpose LDS row stride (halfs): 80B rows -> b128-aligned

using f16x8 = __attribute__((ext_vector_type(8))) _Float16;
using f16x4 = __attribute__((ext_vector_type(4))) _Float16;
using f32x4 = __attribute__((ext_vector_type(4))) float;

// ---------------------------------------------------------------------------
// One-shot fp32 -> f16 cast of 5 tensors.
// ---------------------------------------------------------------------------
__global__ __launch_bounds__(256) void cast_f16_5(
    const float* __restrict__ s0, _Float16* __restrict__ d0, int n0,
    const float* __restrict__ s1, _Float16* __restrict__ d1, int n1,
    const float* __restrict__ s2, _Float16* __restrict__ d2, int n2,
    const float* __restrict__ s3, _Float16* __restrict__ d3, int n3,
    const float* __restrict__ s4, _Float16* __restrict__ d4, int n4) {
  const int q0 = n0 >> 2, q1 = n1 >> 2, q2 = n2 >> 2, q3 = n3 >> 2, q4 = n4 >> 2;
  const int total = q0 + q1 + q2 + q3 + q4;
  for (int i = blockIdx.x * 256 + threadIdx.x; i < total;
       i += gridDim.x * 256) {
    int j = i;
    const float* s;
    _Float16* d;
    if (j < q0) { s = s0; d = d0; }
    else { j -= q0;
      if (j < q1) { s = s1; d = d1; }
      else { j -= q1;
        if (j < q2) { s = s2; d = d2; }
        else { j -= q2;
          if (j < q3) { s = s3; d = d3; }
          else { j -= q3; s = s4; d = d4; } } } }
    float4 v = *(const float4*)&s[(size_t)j * 4];
    *(f16x4*)&d[(size_t)j * 4] =
        f16x4{(_Float16)v.x, (_Float16)v.y, (_Float16)v.z, (_Float16)v.w};
  }
}

// ---------------------------------------------------------------------------
// Pure-f16 NT GEMM (unchanged from R5).
// ---------------------------------------------------------------------------
__global__ __launch_bounds__(256) void gemm_ff16(
    const _Float16* __restrict__ A, const _Float16* __restrict__ B,
    const float* __restrict__ bias, _Float16* __restrict__ C,
    int M, int N, int K) {
  __shared__ _Float16 As[128 * GLDH];
  __shared__ _Float16 Bs[64 * GLDH];
  const int tid = threadIdx.x, lane = tid & 63, wid = tid >> 6;
  const int bm = blockIdx.y * 128, bn = blockIdx.x * 64;
  const int wr = (wid >> 1) * 64, wc = (wid & 1) * 32;
  const int lrow = lane & 15, lk = (lane >> 4) * 8;

  f16x8 ra[4], rb[2];
#pragma unroll
  for (int i = 0; i < 4; ++i) {
    int idx = tid + i * 256, r = idx >> 3, c = (idx & 7) * 8;
    ra[i] = *(const f16x8*)&A[(size_t)(bm + r) * K + c];
  }
#pragma unroll
  for (int i = 0; i < 2; ++i) {
    int idx = tid + i * 256, r = idx >> 3, c = (idx & 7) * 8;
    rb[i] = *(const f16x8*)&B[(size_t)(bn + r) * K + c];
  }

  f32x4 acc[4][2] = {};
  for (int k0 = 0; k0 < K; k0 += 64) {
#pragma unroll
    for (int i = 0; i < 4; ++i) {
      int idx = tid + i * 256, r = idx >> 3, c = (idx & 7) * 8;
      *(f16x8*)&As[r * GLDH + c] = ra[i];
    }
#pragma unroll
    for (int i = 0; i < 2; ++i) {
      int idx = tid + i * 256, r = idx >> 3, c = (idx & 7) * 8;
      *(f16x8*)&Bs[r * GLDH + c] = rb[i];
    }
    __syncthreads();
    if (k0 + 64 < K) {
#pragma unroll
      for (int i = 0; i < 4; ++i) {
        int idx = tid + i * 256, r = idx >> 3, c = (idx & 7) * 8;
        ra[i] = *(const f16x8*)&A[(size_t)(bm + r) * K + k0 + 64 + c];
      }
#pragma unroll
      for (int i = 0; i < 2; ++i) {
        int idx = tid + i * 256, r = idx >> 3, c = (idx & 7) * 8;
        rb[i] = *(const f16x8*)&B[(size_t)(bn + r) * K + k0 + 64 + c];
      }
    }
    f16x8 a[4][2], b[2][2];
#pragma unroll
    for (int mi = 0; mi < 4; ++mi)
#pragma unroll
      for (int ks = 0; ks < 2; ++ks)
        a[mi][ks] = *(const f16x8*)&As[(wr + mi * 16 + lrow) * GLDH + ks * 32 + lk];
#pragma unroll
    for (int ni = 0; ni < 2; ++ni)
#pragma unroll
      for (int ks = 0; ks < 2; ++ks)
        b[ni][ks] = *(const f16x8*)&Bs[(wc + ni * 16 + lrow) * GLDH + ks * 32 + lk];
#pragma unroll
    for (int ks = 0; ks < 2; ++ks)
#pragma unroll
      for (int mi = 0; mi < 4; ++mi)
#pragma unroll
        for (int ni = 0; ni < 2; ++ni)
          acc[mi][ni] = __builtin_amdgcn_mfma_f32_16x16x32_f16(
              a[mi][ks], b[ni][ks], acc[mi][ni], 0, 0, 0);
    __syncthreads();
  }
#pragma unroll
  for (int mi = 0; mi < 4; ++mi)
#pragma unroll
    for (int ni = 0; ni < 2; ++ni) {
      int col = bn + wc + ni * 16 + lrow;
      float bv = bias ? bias[col] : 0.0f;
#pragma unroll
      for (int i = 0; i < 4; ++i) {
        int row = bm + wr + mi * 16 + (lane >> 4) * 4 + i;
        C[(size_t)row * N + col] = (_Float16)(acc[mi][ni][i] + bv);
      }
    }
}

// ---------------------------------------------------------------------------
// Fully fused attention: bias(emb·Wg) + qk + online-softmax + PV, no S in HBM.
// Grid: 256 blocks (split = bid&7 -> XCD-local K/V slice; nt = bid>>3).
// Block: 512 threads = 8 waves; wave w owns groups {2w, 2w+1}; all waves
// traverse the block's full m-range (512) so each (n,g) row's online state
// lives entirely in one wave. Partials (acc, m, l) -> HBM; combine kernel.
// ---------------------------------------------------------------------------
__global__ __launch_bounds__(512) void attn_fused_kernel(
    const float* __restrict__ rois_cur, const float* __restrict__ rois_ref,
    const float* __restrict__ Wg_w, const float* __restrict__ Wg_b,
    const _Float16* __restrict__ q, const _Float16* __restrict__ k,
    const _Float16* __restrict__ vt, float* __restrict__ pacc,
    float* __restrict__ pml) {
  __shared__ _Float16 Bias[GROUP][16][BP2];  // [g][n_local][m_chunk 128 + pad]
  __shared__ _Float16 pt[8][16][PTP];        // per-wave P transpose buffer
  const int tid = threadIdx.x, lane = tid & 63, w = tid >> 6;
  const int bid = blockIdx.x;
  const int split = bid & 7, nt = bid >> 3;
  const int n0 = nt * 16;
  const int mb0 = split * MRANGE;
  const int lm = lane & 15, lc = lane >> 4;
  const int g0 = w * 2;

  // Wg A-fragments (row g = lm) + per-C-row bias values
  f16x8 wgf[2];
#pragma unroll
  for (int kc = 0; kc < 2; ++kc) {
    const float* p = Wg_w + lm * EMB + kc * 32 + lc * 8;
#pragma unroll
    for (int j = 0; j < 8; ++j) wgf[kc][j] = (_Float16)p[j];
  }
  float wgb[4];
#pragma unroll
  for (int i = 0; i < 4; ++i) wgb[i] = Wg_b[lc * 4 + i];

  // Q B-fragments for the wave's two groups (col n = lm), hoisted
  f16x8 qb[2][2];
#pragma unroll
  for (int gi = 0; gi < 2; ++gi)
#pragma unroll
    for (int kc = 0; kc < 2; ++kc)
      qb[gi][kc] = *(const f16x8*)
          &q[(size_t)(n0 + lm) * FEAT + (g0 + gi) * DG + kc * 32 + lc * 8];

  f32x4 acc[2][4] = {};
  float mrun[2] = {-1e30f, -1e30f}, lrun[2] = {0.0f, 0.0f};

  const float inv_dim[8] = {1.0f,          0.42169651f,  0.17782794f,
                            0.074989417f,  0.031622776f, 0.013335214f,
                            0.0056234133f, 0.0023713737f};
  const int isY = lc >> 1;
  const int useCos = lc & 1;

  for (int ch = 0; ch < MRANGE / MCHUNK; ++ch) {
    const int cb = mb0 + ch * MCHUNK;
    const int mglob = cb + w * 16 + lm;  // this lane's bias m-column

    const float4 rb = reinterpret_cast<const float4*>(rois_ref)[mglob];
    const float wr_ = rb.z - rb.x + 1.0f, hr_ = rb.w - rb.y + 1.0f;
    const float cxr = 0.5f * (rb.x + rb.z), cyr = 0.5f * (rb.y + rb.w);
    const float lwr = __logf(wr_), lhr = __logf(hr_);

    __syncthreads();  // previous chunk fully consumed before overwrite

    // ---- bias phase: wave covers m-cols [w*16, w*16+16), all 16 g, 16 n ----
    for (int nl = 0; nl < 16; ++nl) {
      const int n = n0 + nl;
      const float x0 = rois_cur[n * 4 + 0], y0 = rois_cur[n * 4 + 1];
      const float x1 = rois_cur[n * 4 + 2], y1 = rois_cur[n * 4 + 3];
      const float ww = x1 - x0 + 1.0f, hh = y1 - y0 + 1.0f;
      const float cx = 0.5f * (x0 + x1), cy = 0.5f * (y0 + y1);
      float pa, pb;
      if (isY) {
        pa = __logf(fabsf((cy - cyr) / hh) + 0.001f);
        pb = __logf(hh) - lhr;
      } else {
        pa = __logf(fabsf((cx - cxr) / ww) + 0.001f);
        pb = __logf(ww) - lwr;
      }
      pa *= 100.0f;
      pb *= 100.0f;
      f16x8 ef0, ef1;
#pragma unroll
      for (int f = 0; f < 8; ++f) {
        const float xa = pa * inv_dim[f];
        const float xb = pb * inv_dim[f];
        ef0[f] = (_Float16)(useCos ? __cosf(xa) : __sinf(xa));
        ef1[f] = (_Float16)(useCos ? __cosf(xb) : __sinf(xb));
      }
      f32x4 bacc = {};
      bacc = __builtin_amdgcn_mfma_f32_16x16x32_f16(wgf[0], ef0, bacc, 0, 0, 0);
      bacc = __builtin_amdgcn_mfma_f32_16x16x32_f16(wgf[1], ef1, bacc, 0, 0, 0);
#pragma unroll
      for (int i = 0; i < 4; ++i) {
        float v = fmaxf(bacc[i] + wgb[i], 0.0f);
        Bias[lc * 4 + i][nl][w * 16 + lm] = (_Float16)__logf(v + 1e-6f);
      }
    }
    __syncthreads();

    // ---- consume: 4 steps x 32 m; swapped qk -> softmax -> PV ----
    for (int st = 0; st < 4; ++st) {
      const int ms = cb + st * 32;
#pragma unroll
      for (int gi = 0; gi < 2; ++gi) {
        const int g = g0 + gi;
        // K A-fragments (row m), two 16-m subtiles x two 32-d chunks
        const size_t kbase = (size_t)(ms + lm) * FEAT + g * DG + lc * 8;
        f16x8 ka0a = *(const f16x8*)&k[kbase];
        f16x8 ka0b = *(const f16x8*)&k[kbase + 32];
        f16x8 ka1a = *(const f16x8*)&k[kbase + (size_t)16 * FEAT];
        f16x8 ka1b = *(const f16x8*)&k[kbase + (size_t)16 * FEAT + 32];
        f32x4 sAa = {}, sBa = {};
        sAa = __builtin_amdgcn_mfma_f32_16x16x32_f16(ka0a, qb[gi][0], sAa, 0, 0, 0);
        sAa = __builtin_amdgcn_mfma_f32_16x16x32_f16(ka0b, qb[gi][1], sAa, 0, 0, 0);
        sBa = __builtin_amdgcn_mfma_f32_16x16x32_f16(ka1a, qb[gi][0], sBa, 0, 0, 0);
        sBa = __builtin_amdgcn_mfma_f32_16x16x32_f16(ka1b, qb[gi][1], sBa, 0, 0, 0);
        // bias add (C rows = m = lc*4+i, col n = lm)
        const f16x4 bA = *(const f16x4*)&Bias[g][lm][st * 32 + lc * 4];
        const f16x4 bB = *(const f16x4*)&Bias[g][lm][st * 32 + 16 + lc * 4];
        float s[8];
#pragma unroll
        for (int i = 0; i < 4; ++i) {
          s[i] = (float)bA[i] + sAa[i] * 0.125f;
          s[4 + i] = (float)bB[i] + sBa[i] * 0.125f;
        }
        // online softmax over this 32-m step (rows n = lm)
        float cmax = s[0];
#pragma unroll
        for (int i = 1; i < 8; ++i) cmax = fmaxf(cmax, s[i]);
        cmax = fmaxf(cmax, __shfl_xor(cmax, 16));
        cmax = fmaxf(cmax, __shfl_xor(cmax, 32));
        const float mnew = fmaxf(mrun[gi], cmax);
        const float fac = __expf(mrun[gi] - mnew);
        float p[8];
        float csum = 0.0f;
#pragma unroll
        for (int i = 0; i < 8; ++i) {
          p[i] = __expf(s[i] - mnew);
          csum += p[i];
        }
        csum += __shfl_xor(csum, 16);
        csum += __shfl_xor(csum, 32);
        lrun[gi] = lrun[gi] * fac + csum;
        mrun[gi] = mnew;
        // rescale existing acc (acc rows n = lc*4+i)
        float fr[4];
#pragma unroll
        for (int i = 0; i < 4; ++i) fr[i] = __shfl(fac, lc * 4 + i);
#pragma unroll
        for (int ct = 0; ct < 4; ++ct)
#pragma unroll
          for (int i = 0; i < 4; ++i) acc[gi][ct][i] *= fr[i];
        // P -> f16, transpose via per-wave LDS to A-frag layout
        f16x4 pA = {(_Float16)p[0], (_Float16)p[1], (_Float16)p[2], (_Float16)p[3]};
        f16x4 pB = {(_Float16)p[4], (_Float16)p[5], (_Float16)p[6], (_Float16)p[7]};
        *(f16x4*)&pt[w][lm][lc * 4] = pA;
        *(f16x4*)&pt[w][lm][16 + lc * 4] = pB;
        const f16x8 pfrag = *(const f16x8*)&pt[w][lm][lc * 8];
        // V B-fragments + PV MFMAs
#pragma unroll
        for (int ct = 0; ct < 4; ++ct) {
          const f16x8 vf = *(const f16x8*)
              &vt[(size_t)(g * DG + ct * 16 + lm) * M_REF + ms + lc * 8];
          acc[gi][ct] = __builtin_amdgcn_mfma_f32_16x16x32_f16(pfrag, vf,
                                                              acc[gi][ct], 0, 0, 0);
        }
      }
    }
  }

  // ---- write partials ----
#pragma unroll
  for (int gi = 0; gi < 2; ++gi) {
    const size_t base = (size_t)(nt * GROUP + g0 + gi) * MSPLIT + split;
#pragma unroll
    for (int ct = 0; ct < 4; ++ct)
#pragma unroll
      for (int i = 0; i < 4; ++i)
        pacc[(base * 16 + lc * 4 + i) * 64 + ct * 16 + lm] = acc[gi][ct][i];
    if (lc == 0) {
      pml[(base * 16 + lm) * 2 + 0] = mrun[gi];
      pml[(base * 16 + lm) * 2 + 1] = lrun[gi];
    }
  }
}

// ---------------------------------------------------------------------------
// LSE combine over MSPLIT partials + Wv_b.  grid(512): nt = bid>>4, g = bid&15.
// ---------------------------------------------------------------------------
__global__ __launch_bounds__(256) void combine_kernel(
    const float* __restrict__ pacc, const float* __restrict__ pml,
    const float* __restrict__ Wv_b, float* __restrict__ out) {
  const int nt = blockIdx.x >> 4, g = blockIdx.x & 15;
  const int r = threadIdx.x >> 4, c0 = (threadIdx.x & 15) * 4;
  const size_t gb = (size_t)(nt * GROUP + g) * MSPLIT;

  float ms[MSPLIT], ls[MSPLIT];
  float M = -1e30f;
#pragma unroll
  for (int s = 0; s < MSPLIT; ++s) {
    ms[s] = pml[((gb + s) * 16 + r) * 2 + 0];
    ls[s] = pml[((gb + s) * 16 + r) * 2 + 1];
    M = fmaxf(M, ms[s]);
  }
  float e[MSPLIT], D = 0.0f;
#pragma unroll
  for (int s = 0; s < MSPLIT; ++s) {
    e[s] = __expf(ms[s] - M);
    D += e[s] * ls[s];
  }
  const float inv = 1.0f / D;
  float4 o = {0.0f, 0.0f, 0.0f, 0.0f};
  float* po = &o.x;
#pragma unroll
  for (int s = 0; s < MSPLIT; ++s) {
    const float4 a = *(const float4*)&pacc[((gb + s) * 16 + r) * 64 + c0];
    po[0] += e[s] * a.x;
    po[1] += e[s] * a.y;
    po[2] += e[s] * a.z;
    po[3] += e[s] * a.w;
  }
#pragma unroll
  for (int j = 0; j < 4; ++j)
    po[j] = po[j] * inv + Wv_b[g * DG + c0 + j];
  *(float4*)&out[(size_t)(nt * 16 + r) * FEAT + g * DG + c0] = o;
}

// ---------------------------------------------------------------------------
extern "C" void kernel_launch(void* const* d_in, const int* in_sizes, int n_in,
                              void* d_out, int out_size, void* d_ws,
                              size_t ws_size, hipStream_t stream) {
  const float* roi_feat = (const float*)d_in[0];   // [512,1024]
  const float* ref_feat = (const float*)d_in[1];   // [4096,1024]
  const float* rois_cur = (const float*)d_in[2];   // [512,4]
  const float* rois_ref = (const float*)d_in[3];   // [4096,4]
  const float* Wg_w = (const float*)d_in[4];       // [16,64]
  const float* Wg_b = (const float*)d_in[5];       // [16]
  const float* Wq_w = (const float*)d_in[6];       // [1024,1024]
  const float* Wq_b = (const float*)d_in[7];       // [1024]
  const float* Wk_w = (const float*)d_in[8];       // [1024,1024]
  const float* Wk_b = (const float*)d_in[9];       // [1024]
  const float* Wv_w = (const float*)d_in[10];      // [1024,1024]
  const float* Wv_b = (const float*)d_in[11];      // [1024]
  float* out = (float*)d_out;                      // [512,1024]

  _Float16* q16 = (_Float16*)d_ws;                     // 512*1024
  _Float16* k16 = q16 + (size_t)N_ROI * FEAT;          // 4096*1024
  _Float16* vt16 = k16 + (size_t)M_REF * FEAT;         // 1024*4096
  _Float16* roi16 = vt16 + (size_t)FEAT * M_REF;       // 512*1024
  _Float16* ref16 = roi16 + (size_t)N_ROI * FEAT;      // 4096*1024
  _Float16* wq16 = ref16 + (size_t)M_REF * FEAT;       // 1024*1024
  _Float16* wk16 = wq16 + (size_t)FEAT * FEAT;         // 1024*1024
  _Float16* wv16 = wk16 + (size_t)FEAT * FEAT;         // 1024*1024
  float* pacc = (float*)(wv16 + (size_t)FEAT * FEAT);  // 512*16*8*... = 4.2M f32
  float* pml = pacc + (size_t)N_ROI * GROUP * MSPLIT * 64;  // 512*16*8*2 f32

  // 0. cast fp32 -> f16 once
  cast_f16_5<<<dim3(2048), 256, 0, stream>>>(
      roi_feat, roi16, N_ROI * FEAT, ref_feat, ref16, M_REF * FEAT,
      Wq_w, wq16, FEAT * FEAT, Wk_w, wk16, FEAT * FEAT,
      Wv_w, wv16, FEAT * FEAT);

  // 1. projections (pure-f16 MFMA GEMMs)
  gemm_ff16<<<dim3(FEAT / 64, N_ROI / 128), 256, 0, stream>>>(
      roi16, wq16, Wq_b, q16, N_ROI, FEAT, FEAT);
  gemm_ff16<<<dim3(FEAT / 64, M_REF / 128), 256, 0, stream>>>(
      ref16, wk16, Wk_b, k16, M_REF, FEAT, FEAT);
  gemm_ff16<<<dim3(M_REF / 64, FEAT / 128), 256, 0, stream>>>(
      wv16, ref16, nullptr, vt16, FEAT, M_REF, FEAT);

  // 2. fused bias + qk + online softmax + PV (no S materialization)
  attn_fused_kernel<<<dim3((N_ROI / 16) * MSPLIT), 512, 0, stream>>>(
      rois_cur, rois_ref, Wg_w, Wg_b, q16, k16, vt16, pacc, pml);

  // 3. LSE combine + Wv bias
  combine_kernel<<<dim3((N_ROI / 16) * GROUP), 256, 0, stream>>>(
      pacc, pml, Wv_b, out);
}

// Round 7
// 270.512 us; speedup vs baseline: 1.0201x; 1.0201x over previous
//
#include <hip/hip_runtime.h>
#include <hip/hip_bf16.h>

#define N_ROI 512
#define M_REF 4096
#define FEAT 1024
#define GROUP 16
#define DG 64
#define EMB 64
#define GLDH 72   // gemm LDS row stride (halfs)
#define MSPLIT 16
#define MRANGE (M_REF / MSPLIT)  // 256
#define MCHUNK 128
#define BP2 136   // bias LDS m-stride (halfs)
#define PTP 40    // P-transpose LDS row stride (halfs)
#define DEFER_THR 8.0f

using f16x8 = __attribute__((ext_vector_type(8))) _Float16;
using f16x4 = __attribute__((ext_vector_type(4))) _Float16;
using f32x4 = __attribute__((ext_vector_type(4))) float;

// ---------------------------------------------------------------------------
// One-shot fp32 -> f16 cast of 5 tensors.
// ---------------------------------------------------------------------------
__global__ __launch_bounds__(256) void cast_f16_5(
    const float* __restrict__ s0, _Float16* __restrict__ d0, int n0,
    const float* __restrict__ s1, _Float16* __restrict__ d1, int n1,
    const float* __restrict__ s2, _Float16* __restrict__ d2, int n2,
    const float* __restrict__ s3, _Float16* __restrict__ d3, int n3,
    const float* __restrict__ s4, _Float16* __restrict__ d4, int n4) {
  const int q0 = n0 >> 2, q1 = n1 >> 2, q2 = n2 >> 2, q3 = n3 >> 2, q4 = n4 >> 2;
  const int total = q0 + q1 + q2 + q3 + q4;
  for (int i = blockIdx.x * 256 + threadIdx.x; i < total;
       i += gridDim.x * 256) {
    int j = i;
    const float* s;
    _Float16* d;
    if (j < q0) { s = s0; d = d0; }
    else { j -= q0;
      if (j < q1) { s = s1; d = d1; }
      else { j -= q1;
        if (j < q2) { s = s2; d = d2; }
        else { j -= q2;
          if (j < q3) { s = s3; d = d3; }
          else { j -= q3; s = s4; d = d4; } } } }
    float4 v = *(const float4*)&s[(size_t)j * 4];
    *(f16x4*)&d[(size_t)j * 4] =
        f16x4{(_Float16)v.x, (_Float16)v.y, (_Float16)v.z, (_Float16)v.w};
  }
}

// ---------------------------------------------------------------------------
// Pure-f16 NT GEMM (unchanged).
// ---------------------------------------------------------------------------
__global__ __launch_bounds__(256) void gemm_ff16(
    const _Float16* __restrict__ A, const _Float16* __restrict__ B,
    const float* __restrict__ bias, _Float16* __restrict__ C,
    int M, int N, int K) {
  __shared__ _Float16 As[128 * GLDH];
  __shared__ _Float16 Bs[64 * GLDH];
  const int tid = threadIdx.x, lane = tid & 63, wid = tid >> 6;
  const int bm = blockIdx.y * 128, bn = blockIdx.x * 64;
  const int wr = (wid >> 1) * 64, wc = (wid & 1) * 32;
  const int lrow = lane & 15, lk = (lane >> 4) * 8;

  f16x8 ra[4], rb[2];
#pragma unroll
  for (int i = 0; i < 4; ++i) {
    int idx = tid + i * 256, r = idx >> 3, c = (idx & 7) * 8;
    ra[i] = *(const f16x8*)&A[(size_t)(bm + r) * K + c];
  }
#pragma unroll
  for (int i = 0; i < 2; ++i) {
    int idx = tid + i * 256, r = idx >> 3, c = (idx & 7) * 8;
    rb[i] = *(const f16x8*)&B[(size_t)(bn + r) * K + c];
  }

  f32x4 acc[4][2] = {};
  for (int k0 = 0; k0 < K; k0 += 64) {
#pragma unroll
    for (int i = 0; i < 4; ++i) {
      int idx = tid + i * 256, r = idx >> 3, c = (idx & 7) * 8;
      *(f16x8*)&As[r * GLDH + c] = ra[i];
    }
#pragma unroll
    for (int i = 0; i < 2; ++i) {
      int idx = tid + i * 256, r = idx >> 3, c = (idx & 7) * 8;
      *(f16x8*)&Bs[r * GLDH + c] = rb[i];
    }
    __syncthreads();
    if (k0 + 64 < K) {
#pragma unroll
      for (int i = 0; i < 4; ++i) {
        int idx = tid + i * 256, r = idx >> 3, c = (idx & 7) * 8;
        ra[i] = *(const f16x8*)&A[(size_t)(bm + r) * K + k0 + 64 + c];
      }
#pragma unroll
      for (int i = 0; i < 2; ++i) {
        int idx = tid + i * 256, r = idx >> 3, c = (idx & 7) * 8;
        rb[i] = *(const f16x8*)&B[(size_t)(bn + r) * K + k0 + 64 + c];
      }
    }
    f16x8 a[4][2], b[2][2];
#pragma unroll
    for (int mi = 0; mi < 4; ++mi)
#pragma unroll
      for (int ks = 0; ks < 2; ++ks)
        a[mi][ks] = *(const f16x8*)&As[(wr + mi * 16 + lrow) * GLDH + ks * 32 + lk];
#pragma unroll
    for (int ni = 0; ni < 2; ++ni)
#pragma unroll
      for (int ks = 0; ks < 2; ++ks)
        b[ni][ks] = *(const f16x8*)&Bs[(wc + ni * 16 + lrow) * GLDH + ks * 32 + lk];
#pragma unroll
    for (int ks = 0; ks < 2; ++ks)
#pragma unroll
      for (int mi = 0; mi < 4; ++mi)
#pragma unroll
        for (int ni = 0; ni < 2; ++ni)
          acc[mi][ni] = __builtin_amdgcn_mfma_f32_16x16x32_f16(
              a[mi][ks], b[ni][ks], acc[mi][ni], 0, 0, 0);
    __syncthreads();
  }
#pragma unroll
  for (int mi = 0; mi < 4; ++mi)
#pragma unroll
    for (int ni = 0; ni < 2; ++ni) {
      int col = bn + wc + ni * 16 + lrow;
      float bv = bias ? bias[col] : 0.0f;
#pragma unroll
      for (int i = 0; i < 4; ++i) {
        int row = bm + wr + mi * 16 + (lane >> 4) * 4 + i;
        C[(size_t)row * N + col] = (_Float16)(acc[mi][ni][i] + bv);
      }
    }
}

// ---------------------------------------------------------------------------
// Fully fused attention: bias(emb·Wg) + qk + online-softmax + PV.
// Grid: 512 blocks (split = bid & 15, nt = bid >> 4) -> 2 blocks/CU.
// Block: 512 threads = 8 waves; wave w owns groups {2w, 2w+1}.
// Defer-max: skip acc rescale while cmax <= mrun + DEFER_THR (wave-uniform).
// ---------------------------------------------------------------------------
__global__ __launch_bounds__(512) void attn_fused_kernel(
    const float* __restrict__ rois_cur, const float* __restrict__ rois_ref,
    const float* __restrict__ Wg_w, const float* __restrict__ Wg_b,
    const _Float16* __restrict__ q, const _Float16* __restrict__ k,
    const _Float16* __restrict__ vt, float* __restrict__ pacc,
    float* __restrict__ pml) {
  __shared__ _Float16 Bias[GROUP][16][BP2];  // [g][n_local][m_chunk 128 + pad]
  __shared__ _Float16 pt[8][16][PTP];        // per-wave P transpose buffer
  const int tid = threadIdx.x, lane = tid & 63, w = tid >> 6;
  const int bid = blockIdx.x;
  const int split = bid & (MSPLIT - 1), nt = bid >> 4;
  const int n0 = nt * 16;
  const int mb0 = split * MRANGE;
  const int lm = lane & 15, lc = lane >> 4;
  const int g0 = w * 2;

  // Wg A-fragments (row g = lm) + per-C-row bias values
  f16x8 wgf[2];
#pragma unroll
  for (int kc = 0; kc < 2; ++kc) {
    const float* p = Wg_w + lm * EMB + kc * 32 + lc * 8;
#pragma unroll
    for (int j = 0; j < 8; ++j) wgf[kc][j] = (_Float16)p[j];
  }
  float wgb[4];
#pragma unroll
  for (int i = 0; i < 4; ++i) wgb[i] = Wg_b[lc * 4 + i];

  // Q B-fragments for the wave's two groups (col n = lm), hoisted
  f16x8 qb[2][2];
#pragma unroll
  for (int gi = 0; gi < 2; ++gi)
#pragma unroll
    for (int kc = 0; kc < 2; ++kc)
      qb[gi][kc] = *(const f16x8*)
          &q[(size_t)(n0 + lm) * FEAT + (g0 + gi) * DG + kc * 32 + lc * 8];

  f32x4 acc[2][4] = {};
  float mrun[2] = {-1e30f, -1e30f}, lrun[2] = {0.0f, 0.0f};

  const float inv_dim[8] = {1.0f,          0.42169651f,  0.17782794f,
                            0.074989417f,  0.031622776f, 0.013335214f,
                            0.0056234133f, 0.0023713737f};
  const int isY = lc >> 1;
  const int useCos = lc & 1;

  for (int ch = 0; ch < MRANGE / MCHUNK; ++ch) {
    const int cb = mb0 + ch * MCHUNK;
    const int mglob = cb + w * 16 + lm;  // this lane's bias m-column

    const float4 rb = reinterpret_cast<const float4*>(rois_ref)[mglob];
    const float wr_ = rb.z - rb.x + 1.0f, hr_ = rb.w - rb.y + 1.0f;
    const float cxr = 0.5f * (rb.x + rb.z), cyr = 0.5f * (rb.y + rb.w);
    const float lwr = __logf(wr_), lhr = __logf(hr_);

    __syncthreads();  // previous chunk fully consumed before overwrite

    // ---- bias phase ----
    for (int nl = 0; nl < 16; ++nl) {
      const int n = n0 + nl;
      const float x0 = rois_cur[n * 4 + 0], y0 = rois_cur[n * 4 + 1];
      const float x1 = rois_cur[n * 4 + 2], y1 = rois_cur[n * 4 + 3];
      const float ww = x1 - x0 + 1.0f, hh = y1 - y0 + 1.0f;
      const float cx = 0.5f * (x0 + x1), cy = 0.5f * (y0 + y1);
      float pa, pb;
      if (isY) {
        pa = __logf(fabsf((cy - cyr) / hh) + 0.001f);
        pb = __logf(hh) - lhr;
      } else {
        pa = __logf(fabsf((cx - cxr) / ww) + 0.001f);
        pb = __logf(ww) - lwr;
      }
      pa *= 100.0f;
      pb *= 100.0f;
      f16x8 ef0, ef1;
#pragma unroll
      for (int f = 0; f < 8; ++f) {
        const float xa = pa * inv_dim[f];
        const float xb = pb * inv_dim[f];
        ef0[f] = (_Float16)(useCos ? __cosf(xa) : __sinf(xa));
        ef1[f] = (_Float16)(useCos ? __cosf(xb) : __sinf(xb));
      }
      f32x4 bacc = {};
      bacc = __builtin_amdgcn_mfma_f32_16x16x32_f16(wgf[0], ef0, bacc, 0, 0, 0);
      bacc = __builtin_amdgcn_mfma_f32_16x16x32_f16(wgf[1], ef1, bacc, 0, 0, 0);
#pragma unroll
      for (int i = 0; i < 4; ++i) {
        float v = fmaxf(bacc[i] + wgb[i], 0.0f);
        Bias[lc * 4 + i][nl][w * 16 + lm] = (_Float16)__logf(v + 1e-6f);
      }
    }
    __syncthreads();

    // ---- consume: 4 steps x 32 m; swapped qk -> softmax -> PV ----
    for (int st = 0; st < 4; ++st) {
      const int ms = cb + st * 32;
#pragma unroll
      for (int gi = 0; gi < 2; ++gi) {
        const int g = g0 + gi;
        const size_t kbase = (size_t)(ms + lm) * FEAT + g * DG + lc * 8;
        f16x8 ka0a = *(const f16x8*)&k[kbase];
        f16x8 ka0b = *(const f16x8*)&k[kbase + 32];
        f16x8 ka1a = *(const f16x8*)&k[kbase + (size_t)16 * FEAT];
        f16x8 ka1b = *(const f16x8*)&k[kbase + (size_t)16 * FEAT + 32];
        f32x4 sAa = {}, sBa = {};
        sAa = __builtin_amdgcn_mfma_f32_16x16x32_f16(ka0a, qb[gi][0], sAa, 0, 0, 0);
        sAa = __builtin_amdgcn_mfma_f32_16x16x32_f16(ka0b, qb[gi][1], sAa, 0, 0, 0);
        sBa = __builtin_amdgcn_mfma_f32_16x16x32_f16(ka1a, qb[gi][0], sBa, 0, 0, 0);
        sBa = __builtin_amdgcn_mfma_f32_16x16x32_f16(ka1b, qb[gi][1], sBa, 0, 0, 0);
        const f16x4 bA = *(const f16x4*)&Bias[g][lm][st * 32 + lc * 4];
        const f16x4 bB = *(const f16x4*)&Bias[g][lm][st * 32 + 16 + lc * 4];
        float s[8];
#pragma unroll
        for (int i = 0; i < 4; ++i) {
          s[i] = (float)bA[i] + sAa[i] * 0.125f;
          s[4 + i] = (float)bB[i] + sBa[i] * 0.125f;
        }
        float cmax = s[0];
#pragma unroll
        for (int i = 1; i < 8; ++i) cmax = fmaxf(cmax, s[i]);
        cmax = fmaxf(cmax, __shfl_xor(cmax, 16));
        cmax = fmaxf(cmax, __shfl_xor(cmax, 32));
        // defer-max: only rescale when the running max grew by > THR
        if (!__all(cmax <= mrun[gi] + DEFER_THR)) {
          const float mnew = fmaxf(mrun[gi], cmax);
          const float fac = __expf(mrun[gi] - mnew);
          lrun[gi] *= fac;
          float fr[4];
#pragma unroll
          for (int i = 0; i < 4; ++i) fr[i] = __shfl(fac, lc * 4 + i);
#pragma unroll
          for (int ct = 0; ct < 4; ++ct)
#pragma unroll
            for (int i = 0; i < 4; ++i) acc[gi][ct][i] *= fr[i];
          mrun[gi] = mnew;
        }
        float p[8];
        float csum = 0.0f;
#pragma unroll
        for (int i = 0; i < 8; ++i) {
          p[i] = __expf(s[i] - mrun[gi]);
          csum += p[i];
        }
        csum += __shfl_xor(csum, 16);
        csum += __shfl_xor(csum, 32);
        lrun[gi] += csum;
        f16x4 pA = {(_Float16)p[0], (_Float16)p[1], (_Float16)p[2], (_Float16)p[3]};
        f16x4 pB = {(_Float16)p[4], (_Float16)p[5], (_Float16)p[6], (_Float16)p[7]};
        *(f16x4*)&pt[w][lm][lc * 4] = pA;
        *(f16x4*)&pt[w][lm][16 + lc * 4] = pB;
        const f16x8 pfrag = *(const f16x8*)&pt[w][lm][lc * 8];
#pragma unroll
        for (int ct = 0; ct < 4; ++ct) {
          const f16x8 vf = *(const f16x8*)
              &vt[(size_t)(g * DG + ct * 16 + lm) * M_REF + ms + lc * 8];
          acc[gi][ct] = __builtin_amdgcn_mfma_f32_16x16x32_f16(pfrag, vf,
                                                              acc[gi][ct], 0, 0, 0);
        }
      }
    }
  }

  // ---- write partials ----
#pragma unroll
  for (int gi = 0; gi < 2; ++gi) {
    const size_t base = (size_t)(nt * GROUP + g0 + gi) * MSPLIT + split;
#pragma unroll
    for (int ct = 0; ct < 4; ++ct)
#pragma unroll
      for (int i = 0; i < 4; ++i)
        pacc[(base * 16 + lc * 4 + i) * 64 + ct * 16 + lm] = acc[gi][ct][i];
    if (lc == 0) {
      pml[(base * 16 + lm) * 2 + 0] = mrun[gi];
      pml[(base * 16 + lm) * 2 + 1] = lrun[gi];
    }
  }
}

// ---------------------------------------------------------------------------
// LSE combine over MSPLIT partials + Wv_b.  grid(512): nt = bid>>4, g = bid&15.
// ---------------------------------------------------------------------------
__global__ __launch_bounds__(256) void combine_kernel(
    const float* __restrict__ pacc, const float* __restrict__ pml,
    const float* __restrict__ Wv_b, float* __restrict__ out) {
  const int nt = blockIdx.x >> 4, g = blockIdx.x & 15;
  const int r = threadIdx.x >> 4, c0 = (threadIdx.x & 15) * 4;
  const size_t gb = (size_t)(nt * GROUP + g) * MSPLIT;

  float ms[MSPLIT], ls[MSPLIT];
  float M = -1e30f;
#pragma unroll
  for (int s = 0; s < MSPLIT; ++s) {
    ms[s] = pml[((gb + s) * 16 + r) * 2 + 0];
    ls[s] = pml[((gb + s) * 16 + r) * 2 + 1];
    M = fmaxf(M, ms[s]);
  }
  float e[MSPLIT], D = 0.0f;
#pragma unroll
  for (int s = 0; s < MSPLIT; ++s) {
    e[s] = __expf(ms[s] - M);
    D += e[s] * ls[s];
  }
  const float inv = 1.0f / D;
  float4 o = {0.0f, 0.0f, 0.0f, 0.0f};
  float* po = &o.x;
#pragma unroll
  for (int s = 0; s < MSPLIT; ++s) {
    const float4 a = *(const float4*)&pacc[((gb + s) * 16 + r) * 64 + c0];
    po[0] += e[s] * a.x;
    po[1] += e[s] * a.y;
    po[2] += e[s] * a.z;
    po[3] += e[s] * a.w;
  }
#pragma unroll
  for (int j = 0; j < 4; ++j)
    po[j] = po[j] * inv + Wv_b[g * DG + c0 + j];
  *(float4*)&out[(size_t)(nt * 16 + r) * FEAT + g * DG + c0] = o;
}

// ---------------------------------------------------------------------------
extern "C" void kernel_launch(void* const* d_in, const int* in_sizes, int n_in,
                              void* d_out, int out_size, void* d_ws,
                              size_t ws_size, hipStream_t stream) {
  const float* roi_feat = (const float*)d_in[0];   // [512,1024]
  const float* ref_feat = (const float*)d_in[1];   // [4096,1024]
  const float* rois_cur = (const float*)d_in[2];   // [512,4]
  const float* rois_ref = (const float*)d_in[3];   // [4096,4]
  const float* Wg_w = (const float*)d_in[4];       // [16,64]
  const float* Wg_b = (const float*)d_in[5];       // [16]
  const float* Wq_w = (const float*)d_in[6];       // [1024,1024]
  const float* Wq_b = (const float*)d_in[7];       // [1024]
  const float* Wk_w = (const float*)d_in[8];       // [1024,1024]
  const float* Wk_b = (const float*)d_in[9];       // [1024]
  const float* Wv_w = (const float*)d_in[10];      // [1024,1024]
  const float* Wv_b = (const float*)d_in[11];      // [1024]
  float* out = (float*)d_out;                      // [512,1024]

  _Float16* q16 = (_Float16*)d_ws;                     // 512*1024
  _Float16* k16 = q16 + (size_t)N_ROI * FEAT;          // 4096*1024
  _Float16* vt16 = k16 + (size_t)M_REF * FEAT;         // 1024*4096
  _Float16* roi16 = vt16 + (size_t)FEAT * M_REF;       // 512*1024
  _Float16* ref16 = roi16 + (size_t)N_ROI * FEAT;      // 4096*1024
  _Float16* wq16 = ref16 + (size_t)M_REF * FEAT;       // 1024*1024
  _Float16* wk16 = wq16 + (size_t)FEAT * FEAT;         // 1024*1024
  _Float16* wv16 = wk16 + (size_t)FEAT * FEAT;         // 1024*1024
  float* pacc = (float*)(wv16 + (size_t)FEAT * FEAT);  // 512*16*16*64 f32
  float* pml = pacc + (size_t)N_ROI * GROUP * MSPLIT * 64;  // 512*16*16*2 f32

  // 0. cast fp32 -> f16 once
  cast_f16_5<<<dim3(2048), 256, 0, stream>>>(
      roi_feat, roi16, N_ROI * FEAT, ref_feat, ref16, M_REF * FEAT,
      Wq_w, wq16, FEAT * FEAT, Wk_w, wk16, FEAT * FEAT,
      Wv_w, wv16, FEAT * FEAT);

  // 1. projections (pure-f16 MFMA GEMMs)
  gemm_ff16<<<dim3(FEAT / 64, N_ROI / 128), 256, 0, stream>>>(
      roi16, wq16, Wq_b, q16, N_ROI, FEAT, FEAT);
  gemm_ff16<<<dim3(FEAT / 64, M_REF / 128), 256, 0, stream>>>(
      ref16, wk16, Wk_b, k16, M_REF, FEAT, FEAT);
  gemm_ff16<<<dim3(M_REF / 64, FEAT / 128), 256, 0, stream>>>(
      wv16, ref16, nullptr, vt16, FEAT, M_REF, FEAT);

  // 2. fused bias + qk + online softmax + PV (no S materialization)
  attn_fused_kernel<<<dim3((N_ROI / 16) * MSPLIT), 512, 0, stream>>>(
      rois_cur, rois_ref, Wg_w, Wg_b, q16, k16, vt16, pacc, pml);

  // 3. LSE combine + Wv bias
  combine_kernel<<<dim3((N_ROI / 16) * GROUP), 256, 0, stream>>>(
      pacc, pml, Wv_b, out);
}

// Round 8
// 259.735 us; speedup vs baseline: 1.0624x; 1.0415x over previous
//
#include <hip/hip_runtime.h>
#include <hip/hip_bf16.h>

#define N_ROI 512
#define M_REF 4096
#define FEAT 1024
#define GROUP 16
#define DG 64
#define EMB 64
#define GLDH 72   // gemm LDS row stride (halfs)
#define MSPLIT 32
#define MRANGE (M_REF / MSPLIT)  // 128
#define MCHUNK 64
#define BP2 72    // bias LDS m-stride (halfs): 64 + 8 pad
#define PTP 40    // P-transpose LDS row stride (halfs)
#define DEFER_THR 8.0f

using f16x8 = __attribute__((ext_vector_type(8))) _Float16;
using f16x4 = __attribute__((ext_vector_type(4))) _Float16;
using f32x4 = __attribute__((ext_vector_type(4))) float;

// ---------------------------------------------------------------------------
// One-shot fp32 -> f16 cast of 5 tensors.
// ---------------------------------------------------------------------------
__global__ __launch_bounds__(256) void cast_f16_5(
    const float* __restrict__ s0, _Float16* __restrict__ d0, int n0,
    const float* __restrict__ s1, _Float16* __restrict__ d1, int n1,
    const float* __restrict__ s2, _Float16* __restrict__ d2, int n2,
    const float* __restrict__ s3, _Float16* __restrict__ d3, int n3,
    const float* __restrict__ s4, _Float16* __restrict__ d4, int n4) {
  const int q0 = n0 >> 2, q1 = n1 >> 2, q2 = n2 >> 2, q3 = n3 >> 2, q4 = n4 >> 2;
  const int total = q0 + q1 + q2 + q3 + q4;
  for (int i = blockIdx.x * 256 + threadIdx.x; i < total;
       i += gridDim.x * 256) {
    int j = i;
    const float* s;
    _Float16* d;
    if (j < q0) { s = s0; d = d0; }
    else { j -= q0;
      if (j < q1) { s = s1; d = d1; }
      else { j -= q1;
        if (j < q2) { s = s2; d = d2; }
        else { j -= q2;
          if (j < q3) { s = s3; d = d3; }
          else { j -= q3; s = s4; d = d4; } } } }
    float4 v = *(const float4*)&s[(size_t)j * 4];
    *(f16x4*)&d[(size_t)j * 4] =
        f16x4{(_Float16)v.x, (_Float16)v.y, (_Float16)v.z, (_Float16)v.w};
  }
}

// ---------------------------------------------------------------------------
// Pure-f16 NT GEMM (unchanged).
// ---------------------------------------------------------------------------
__global__ __launch_bounds__(256) void gemm_ff16(
    const _Float16* __restrict__ A, const _Float16* __restrict__ B,
    const float* __restrict__ bias, _Float16* __restrict__ C,
    int M, int N, int K) {
  __shared__ _Float16 As[128 * GLDH];
  __shared__ _Float16 Bs[64 * GLDH];
  const int tid = threadIdx.x, lane = tid & 63, wid = tid >> 6;
  const int bm = blockIdx.y * 128, bn = blockIdx.x * 64;
  const int wr = (wid >> 1) * 64, wc = (wid & 1) * 32;
  const int lrow = lane & 15, lk = (lane >> 4) * 8;

  f16x8 ra[4], rb[2];
#pragma unroll
  for (int i = 0; i < 4; ++i) {
    int idx = tid + i * 256, r = idx >> 3, c = (idx & 7) * 8;
    ra[i] = *(const f16x8*)&A[(size_t)(bm + r) * K + c];
  }
#pragma unroll
  for (int i = 0; i < 2; ++i) {
    int idx = tid + i * 256, r = idx >> 3, c = (idx & 7) * 8;
    rb[i] = *(const f16x8*)&B[(size_t)(bn + r) * K + c];
  }

  f32x4 acc[4][2] = {};
  for (int k0 = 0; k0 < K; k0 += 64) {
#pragma unroll
    for (int i = 0; i < 4; ++i) {
      int idx = tid + i * 256, r = idx >> 3, c = (idx & 7) * 8;
      *(f16x8*)&As[r * GLDH + c] = ra[i];
    }
#pragma unroll
    for (int i = 0; i < 2; ++i) {
      int idx = tid + i * 256, r = idx >> 3, c = (idx & 7) * 8;
      *(f16x8*)&Bs[r * GLDH + c] = rb[i];
    }
    __syncthreads();
    if (k0 + 64 < K) {
#pragma unroll
      for (int i = 0; i < 4; ++i) {
        int idx = tid + i * 256, r = idx >> 3, c = (idx & 7) * 8;
        ra[i] = *(const f16x8*)&A[(size_t)(bm + r) * K + k0 + 64 + c];
      }
#pragma unroll
      for (int i = 0; i < 2; ++i) {
        int idx = tid + i * 256, r = idx >> 3, c = (idx & 7) * 8;
        rb[i] = *(const f16x8*)&B[(size_t)(bn + r) * K + k0 + 64 + c];
      }
    }
    f16x8 a[4][2], b[2][2];
#pragma unroll
    for (int mi = 0; mi < 4; ++mi)
#pragma unroll
      for (int ks = 0; ks < 2; ++ks)
        a[mi][ks] = *(const f16x8*)&As[(wr + mi * 16 + lrow) * GLDH + ks * 32 + lk];
#pragma unroll
    for (int ni = 0; ni < 2; ++ni)
#pragma unroll
      for (int ks = 0; ks < 2; ++ks)
        b[ni][ks] = *(const f16x8*)&Bs[(wc + ni * 16 + lrow) * GLDH + ks * 32 + lk];
#pragma unroll
    for (int ks = 0; ks < 2; ++ks)
#pragma unroll
      for (int mi = 0; mi < 4; ++mi)
#pragma unroll
        for (int ni = 0; ni < 2; ++ni)
          acc[mi][ni] = __builtin_amdgcn_mfma_f32_16x16x32_f16(
              a[mi][ks], b[ni][ks], acc[mi][ni], 0, 0, 0);
    __syncthreads();
  }
#pragma unroll
  for (int mi = 0; mi < 4; ++mi)
#pragma unroll
    for (int ni = 0; ni < 2; ++ni) {
      int col = bn + wc + ni * 16 + lrow;
      float bv = bias ? bias[col] : 0.0f;
#pragma unroll
      for (int i = 0; i < 4; ++i) {
        int row = bm + wr + mi * 16 + (lane >> 4) * 4 + i;
        C[(size_t)row * N + col] = (_Float16)(acc[mi][ni][i] + bv);
      }
    }
}

// ---------------------------------------------------------------------------
// Fully fused attention: bias(emb·Wg) + qk + online-softmax + PV.
// Grid: 1024 blocks (split = bid & 31, nt = bid >> 5) -> 4 blocks/CU by grid,
// 3 by LDS (46 KB). Block: 512 threads = 8 waves; wave w owns groups {2w,2w+1}.
// Bias phase (MCHUNK=64): wave w covers m-quarter (w&3) and nl-half (w>>2).
// ---------------------------------------------------------------------------
__global__ __launch_bounds__(512) void attn_fused_kernel(
    const float* __restrict__ rois_cur, const float* __restrict__ rois_ref,
    const float* __restrict__ Wg_w, const float* __restrict__ Wg_b,
    const _Float16* __restrict__ q, const _Float16* __restrict__ k,
    const _Float16* __restrict__ vt, float* __restrict__ pacc,
    float* __restrict__ pml) {
  __shared__ _Float16 Bias[GROUP][16][BP2];  // [g][n_local][m_chunk 64 + pad]
  __shared__ _Float16 pt[8][16][PTP];        // per-wave P transpose buffer
  const int tid = threadIdx.x, lane = tid & 63, w = tid >> 6;
  const int bid = blockIdx.x;
  const int split = bid & (MSPLIT - 1), nt = bid >> 5;
  const int n0 = nt * 16;
  const int mb0 = split * MRANGE;
  const int lm = lane & 15, lc = lane >> 4;
  const int g0 = w * 2;
  const int mq = w & 3;        // bias m-quarter within 64-m chunk
  const int nh = (w >> 2) * 8; // bias nl-half base

  // Wg A-fragments (row g = lm) + per-C-row bias values
  f16x8 wgf[2];
#pragma unroll
  for (int kc = 0; kc < 2; ++kc) {
    const float* p = Wg_w + lm * EMB + kc * 32 + lc * 8;
#pragma unroll
    for (int j = 0; j < 8; ++j) wgf[kc][j] = (_Float16)p[j];
  }
  float wgb[4];
#pragma unroll
  for (int i = 0; i < 4; ++i) wgb[i] = Wg_b[lc * 4 + i];

  // Q B-fragments for the wave's two groups (col n = lm), hoisted
  f16x8 qb[2][2];
#pragma unroll
  for (int gi = 0; gi < 2; ++gi)
#pragma unroll
    for (int kc = 0; kc < 2; ++kc)
      qb[gi][kc] = *(const f16x8*)
          &q[(size_t)(n0 + lm) * FEAT + (g0 + gi) * DG + kc * 32 + lc * 8];

  f32x4 acc[2][4] = {};
  float mrun[2] = {-1e30f, -1e30f}, lrun[2] = {0.0f, 0.0f};

  const float inv_dim[8] = {1.0f,          0.42169651f,  0.17782794f,
                            0.074989417f,  0.031622776f, 0.013335214f,
                            0.0056234133f, 0.0023713737f};
  const int isY = lc >> 1;
  const int useCos = lc & 1;

  for (int ch = 0; ch < MRANGE / MCHUNK; ++ch) {
    const int cb = mb0 + ch * MCHUNK;
    const int mglob = cb + mq * 16 + lm;  // this lane's bias m-column

    const float4 rb = reinterpret_cast<const float4*>(rois_ref)[mglob];
    const float wr_ = rb.z - rb.x + 1.0f, hr_ = rb.w - rb.y + 1.0f;
    const float cxr = 0.5f * (rb.x + rb.z), cyr = 0.5f * (rb.y + rb.w);
    const float lwr = __logf(wr_), lhr = __logf(hr_);

    __syncthreads();  // previous chunk fully consumed before overwrite

    // ---- bias phase: wave covers m-quarter mq, nl in [nh, nh+8) ----
    for (int nl = nh; nl < nh + 8; ++nl) {
      const int n = n0 + nl;
      const float x0 = rois_cur[n * 4 + 0], y0 = rois_cur[n * 4 + 1];
      const float x1 = rois_cur[n * 4 + 2], y1 = rois_cur[n * 4 + 3];
      const float ww = x1 - x0 + 1.0f, hh = y1 - y0 + 1.0f;
      const float cx = 0.5f * (x0 + x1), cy = 0.5f * (y0 + y1);
      float pa, pb;
      if (isY) {
        pa = __logf(fabsf((cy - cyr) / hh) + 0.001f);
        pb = __logf(hh) - lhr;
      } else {
        pa = __logf(fabsf((cx - cxr) / ww) + 0.001f);
        pb = __logf(ww) - lwr;
      }
      pa *= 100.0f;
      pb *= 100.0f;
      f16x8 ef0, ef1;
#pragma unroll
      for (int f = 0; f < 8; ++f) {
        const float xa = pa * inv_dim[f];
        const float xb = pb * inv_dim[f];
        ef0[f] = (_Float16)(useCos ? __cosf(xa) : __sinf(xa));
        ef1[f] = (_Float16)(useCos ? __cosf(xb) : __sinf(xb));
      }
      f32x4 bacc = {};
      bacc = __builtin_amdgcn_mfma_f32_16x16x32_f16(wgf[0], ef0, bacc, 0, 0, 0);
      bacc = __builtin_amdgcn_mfma_f32_16x16x32_f16(wgf[1], ef1, bacc, 0, 0, 0);
#pragma unroll
      for (int i = 0; i < 4; ++i) {
        float v = fmaxf(bacc[i] + wgb[i], 0.0f);
        Bias[lc * 4 + i][nl][mq * 16 + lm] = (_Float16)__logf(v + 1e-6f);
      }
    }
    __syncthreads();

    // ---- consume: 2 steps x 32 m; swapped qk -> softmax -> PV ----
    for (int st = 0; st < 2; ++st) {
      const int ms = cb + st * 32;
#pragma unroll
      for (int gi = 0; gi < 2; ++gi) {
        const int g = g0 + gi;
        const size_t kbase = (size_t)(ms + lm) * FEAT + g * DG + lc * 8;
        f16x8 ka0a = *(const f16x8*)&k[kbase];
        f16x8 ka0b = *(const f16x8*)&k[kbase + 32];
        f16x8 ka1a = *(const f16x8*)&k[kbase + (size_t)16 * FEAT];
        f16x8 ka1b = *(const f16x8*)&k[kbase + (size_t)16 * FEAT + 32];
        f32x4 sAa = {}, sBa = {};
        sAa = __builtin_amdgcn_mfma_f32_16x16x32_f16(ka0a, qb[gi][0], sAa, 0, 0, 0);
        sAa = __builtin_amdgcn_mfma_f32_16x16x32_f16(ka0b, qb[gi][1], sAa, 0, 0, 0);
        sBa = __builtin_amdgcn_mfma_f32_16x16x32_f16(ka1a, qb[gi][0], sBa, 0, 0, 0);
        sBa = __builtin_amdgcn_mfma_f32_16x16x32_f16(ka1b, qb[gi][1], sBa, 0, 0, 0);
        const f16x4 bA = *(const f16x4*)&Bias[g][lm][st * 32 + lc * 4];
        const f16x4 bB = *(const f16x4*)&Bias[g][lm][st * 32 + 16 + lc * 4];
        float s[8];
#pragma unroll
        for (int i = 0; i < 4; ++i) {
          s[i] = (float)bA[i] + sAa[i] * 0.125f;
          s[4 + i] = (float)bB[i] + sBa[i] * 0.125f;
        }
        float cmax = s[0];
#pragma unroll
        for (int i = 1; i < 8; ++i) cmax = fmaxf(cmax, s[i]);
        cmax = fmaxf(cmax, __shfl_xor(cmax, 16));
        cmax = fmaxf(cmax, __shfl_xor(cmax, 32));
        // defer-max: only rescale when the running max grew by > THR
        if (!__all(cmax <= mrun[gi] + DEFER_THR)) {
          const float mnew = fmaxf(mrun[gi], cmax);
          const float fac = __expf(mrun[gi] - mnew);
          lrun[gi] *= fac;
          float fr[4];
#pragma unroll
          for (int i = 0; i < 4; ++i) fr[i] = __shfl(fac, lc * 4 + i);
#pragma unroll
          for (int ct = 0; ct < 4; ++ct)
#pragma unroll
            for (int i = 0; i < 4; ++i) acc[gi][ct][i] *= fr[i];
          mrun[gi] = mnew;
        }
        float p[8];
        float csum = 0.0f;
#pragma unroll
        for (int i = 0; i < 8; ++i) {
          p[i] = __expf(s[i] - mrun[gi]);
          csum += p[i];
        }
        csum += __shfl_xor(csum, 16);
        csum += __shfl_xor(csum, 32);
        lrun[gi] += csum;
        f16x4 pA = {(_Float16)p[0], (_Float16)p[1], (_Float16)p[2], (_Float16)p[3]};
        f16x4 pB = {(_Float16)p[4], (_Float16)p[5], (_Float16)p[6], (_Float16)p[7]};
        *(f16x4*)&pt[w][lm][lc * 4] = pA;
        *(f16x4*)&pt[w][lm][16 + lc * 4] = pB;
        const f16x8 pfrag = *(const f16x8*)&pt[w][lm][lc * 8];
#pragma unroll
        for (int ct = 0; ct < 4; ++ct) {
          const f16x8 vf = *(const f16x8*)
              &vt[(size_t)(g * DG + ct * 16 + lm) * M_REF + ms + lc * 8];
          acc[gi][ct] = __builtin_amdgcn_mfma_f32_16x16x32_f16(pfrag, vf,
                                                              acc[gi][ct], 0, 0, 0);
        }
      }
    }
  }

  // ---- write partials ----
#pragma unroll
  for (int gi = 0; gi < 2; ++gi) {
    const size_t base = (size_t)(nt * GROUP + g0 + gi) * MSPLIT + split;
#pragma unroll
    for (int ct = 0; ct < 4; ++ct)
#pragma unroll
      for (int i = 0; i < 4; ++i)
        pacc[(base * 16 + lc * 4 + i) * 64 + ct * 16 + lm] = acc[gi][ct][i];
    if (lc == 0) {
      pml[(base * 16 + lm) * 2 + 0] = mrun[gi];
      pml[(base * 16 + lm) * 2 + 1] = lrun[gi];
    }
  }
}

// ---------------------------------------------------------------------------
// LSE combine over MSPLIT partials + Wv_b.  grid(512): nt = bid>>4, g = bid&15.
// ---------------------------------------------------------------------------
__global__ __launch_bounds__(256) void combine_kernel(
    const float* __restrict__ pacc, const float* __restrict__ pml,
    const float* __restrict__ Wv_b, float* __restrict__ out) {
  const int nt = blockIdx.x >> 4, g = blockIdx.x & 15;
  const int r = threadIdx.x >> 4, c0 = (threadIdx.x & 15) * 4;
  const size_t gb = (size_t)(nt * GROUP + g) * MSPLIT;

  float ms[MSPLIT], ls[MSPLIT];
  float M = -1e30f;
#pragma unroll
  for (int s = 0; s < MSPLIT; ++s) {
    ms[s] = pml[((gb + s) * 16 + r) * 2 + 0];
    ls[s] = pml[((gb + s) * 16 + r) * 2 + 1];
    M = fmaxf(M, ms[s]);
  }
  const float inv_base = 1.0f;
  float D = 0.0f;
  float4 o = {0.0f, 0.0f, 0.0f, 0.0f};
  float* po = &o.x;
#pragma unroll
  for (int s = 0; s < MSPLIT; ++s) {
    const float e = __expf(ms[s] - M);
    D += e * ls[s];
    const float4 a = *(const float4*)&pacc[((gb + s) * 16 + r) * 64 + c0];
    po[0] += e * a.x;
    po[1] += e * a.y;
    po[2] += e * a.z;
    po[3] += e * a.w;
  }
  const float inv = inv_base / D;
#pragma unroll
  for (int j = 0; j < 4; ++j)
    po[j] = po[j] * inv + Wv_b[g * DG + c0 + j];
  *(float4*)&out[(size_t)(nt * 16 + r) * FEAT + g * DG + c0] = o;
}

// ---------------------------------------------------------------------------
extern "C" void kernel_launch(void* const* d_in, const int* in_sizes, int n_in,
                              void* d_out, int out_size, void* d_ws,
                              size_t ws_size, hipStream_t stream) {
  const float* roi_feat = (const float*)d_in[0];   // [512,1024]
  const float* ref_feat = (const float*)d_in[1];   // [4096,1024]
  const float* rois_cur = (const float*)d_in[2];   // [512,4]
  const float* rois_ref = (const float*)d_in[3];   // [4096,4]
  const float* Wg_w = (const float*)d_in[4];       // [16,64]
  const float* Wg_b = (const float*)d_in[5];       // [16]
  const float* Wq_w = (const float*)d_in[6];       // [1024,1024]
  const float* Wq_b = (const float*)d_in[7];       // [1024]
  const float* Wk_w = (const float*)d_in[8];       // [1024,1024]
  const float* Wk_b = (const float*)d_in[9];       // [1024]
  const float* Wv_w = (const float*)d_in[10];      // [1024,1024]
  const float* Wv_b = (const float*)d_in[11];      // [1024]
  float* out = (float*)d_out;                      // [512,1024]

  _Float16* q16 = (_Float16*)d_ws;                     // 512*1024
  _Float16* k16 = q16 + (size_t)N_ROI * FEAT;          // 4096*1024
  _Float16* vt16 = k16 + (size_t)M_REF * FEAT;         // 1024*4096
  _Float16* roi16 = vt16 + (size_t)FEAT * M_REF;       // 512*1024
  _Float16* ref16 = roi16 + (size_t)N_ROI * FEAT;      // 4096*1024
  _Float16* wq16 = ref16 + (size_t)M_REF * FEAT;       // 1024*1024
  _Float16* wk16 = wq16 + (size_t)FEAT * FEAT;         // 1024*1024
  _Float16* wv16 = wk16 + (size_t)FEAT * FEAT;         // 1024*1024
  float* pacc = (float*)(wv16 + (size_t)FEAT * FEAT);  // 512*16*32*64 f32
  float* pml = pacc + (size_t)N_ROI * GROUP * MSPLIT * 64;  // 512*16*32*2 f32

  // 0. cast fp32 -> f16 once
  cast_f16_5<<<dim3(2048), 256, 0, stream>>>(
      roi_feat, roi16, N_ROI * FEAT, ref_feat, ref16, M_REF * FEAT,
      Wq_w, wq16, FEAT * FEAT, Wk_w, wk16, FEAT * FEAT,
      Wv_w, wv16, FEAT * FEAT);

  // 1. projections (pure-f16 MFMA GEMMs)
  gemm_ff16<<<dim3(FEAT / 64, N_ROI / 128), 256, 0, stream>>>(
      roi16, wq16, Wq_b, q16, N_ROI, FEAT, FEAT);
  gemm_ff16<<<dim3(FEAT / 64, M_REF / 128), 256, 0, stream>>>(
      ref16, wk16, Wk_b, k16, M_REF, FEAT, FEAT);
  gemm_ff16<<<dim3(M_REF / 64, FEAT / 128), 256, 0, stream>>>(
      wv16, ref16, nullptr, vt16, FEAT, M_REF, FEAT);

  // 2. fused bias + qk + online softmax + PV (no S materialization)
  attn_fused_kernel<<<dim3((N_ROI / 16) * MSPLIT), 512, 0, stream>>>(
      rois_cur, rois_ref, Wg_w, Wg_b, q16, k16, vt16, pacc, pml);

  // 3. LSE combine + Wv bias
  combine_kernel<<<dim3((N_ROI / 16) * GROUP), 256, 0, stream>>>(
      pacc, pml, Wv_b, out);
}